// Round 9
// baseline (35.670 us; speedup 1.0000x reference)
//
#include <hip/hip_runtime.h>

#define EPS        1e-5f
#define DW_THRESH  4.0f
#define PW_THRESH  0.001f
#define CIN        512
#define COUT       512
#define HWPLANE    784   // 28*28

// ===========================================================================
// Kernel A: per-(b,c) plane flags + speculative constant output fill.
// One block per (b, 32-channel word): 1024 blocks, 4 waves, wave-autonomous
// flags loop (ballot bound check, exact conv fallback). The constant fill of
// this block's 32 output planes is INTERLEAVED into the 8-plane flags loop
// (3 float4 stores per thread per iteration + remainder) so the write stream
// flows from t=0 instead of after the read phase. Kernel B fixes up iff
// mask != 0 (never, with this data).
// ===========================================================================
__global__ __launch_bounds__(256) void flags_fill_kernel(
    const float* __restrict__ x,
    const float* __restrict__ dw_w, const float* __restrict__ dw_b,
    const float* __restrict__ bn1_g, const float* __restrict__ bn1_b,
    const float* __restrict__ bn1_m, const float* __restrict__ bn1_v,
    const float* __restrict__ pw_b,
    const float* __restrict__ bn2_g, const float* __restrict__ bn2_b,
    const float* __restrict__ bn2_m, const float* __restrict__ bn2_v,
    unsigned int* __restrict__ mask,
    float* __restrict__ out)
{
    const int bid  = blockIdx.x;       // b*16 + word
    const int word = bid & 15;
    const int tid  = threadIdx.x;
    const int wv   = tid >> 6;         // wave 0..3
    const int lane = tid & 63;

    __shared__ float tile[4][30 * 28]; // per-wave padded plane (rows -1..28)
    __shared__ float2 sAB[32];         // per-channel (A,B) bound constants
    __shared__ float  sconst[32];      // per-output-channel constant value
    __shared__ unsigned int wflags[4];

    float* tp = tile[wv] + 28;         // tp[r*28 + c], r in [-1, 28]

    // per-channel constants (once per block)
    if (tid < 32) {
        const int   c    = word * 32 + tid;
        const float inv1 = bn1_g[c] * rsqrtf(bn1_v[c] + EPS);
        const float c1   = (dw_b[c] - bn1_m[c]) * inv1 + bn1_b[c];
        float S = 0.0f;
        #pragma unroll
        for (int k = 0; k < 9; ++k) S += fabsf(dw_w[c * 9 + k]);
        sAB[tid] = make_float2(fabsf(inv1) * S, c1);

        // speculative output constant for co = word*32 + tid
        const float inv2 = bn2_g[c] * rsqrtf(bn2_v[c] + EPS);
        const float c2   = (pw_b[c] - bn2_m[c]) * inv2 + bn2_b[c];
        float vv = c2 > 0.0f ? c2 : 0.0f;          // ReLU
        if (vv < PW_THRESH) vv = 0.0f;             // constant-plane prune
        sconst[tid] = vv;
    }
    // zero the two halo rows of the wave tile
    if (lane < 28)      tile[wv][lane] = 0.0f;                 // row -1
    else if (lane < 56) tile[wv][29 * 28 + lane - 28] = 0.0f;  // row 28
    __syncthreads();

    const float* xw = x + ((size_t)bid * 32 + (size_t)wv * 8) * HWPLANE;
    float*       ob = out + (size_t)bid * 32 * HWPLANE;   // 32 output planes

    // conv work assignment (exact path): lane -> (col pair j, row group g)
    const int   j   = lane % 14;                   // cols 2j, 2j+1
    const int   gg  = lane / 14;                   // 0..4 (56-63 duplicate g=3)
    const int   r0  = (gg < 4 ? gg : 3) * 7;       // rows r0 .. r0+6
    const float mLm = (j > 0)  ? 1.0f : 0.0f;
    const float mRm = (j < 13) ? 1.0f : 0.0f;
    const int   pL  = (j > 0)  ? 2 * j - 2 : 0;    // clamped (masked)
    const int   pC  = 2 * j;
    const int   pR  = (j < 13) ? 2 * j + 2 : 24;   // clamped (masked)

    // prefetch plane 0 (196 float4 slots; slot 192+(lane&3) duplicated)
    float4 v0 = ((const float4*)xw)[lane];
    float4 v1 = ((const float4*)xw)[lane + 64];
    float4 v2 = ((const float4*)xw)[lane + 128];
    float4 v3 = ((const float4*)xw)[192 + (lane & 3)];

    unsigned int flags = 0;

    for (int p = 0; p < 8; ++p) {
        // prefetch next plane first (overlaps everything below)
        float4 n0, n1, n2, n3;
        if (p < 7) {
            const float* xn = xw + (size_t)(p + 1) * HWPLANE;
            n0 = ((const float4*)xn)[lane];
            n1 = ((const float4*)xn)[lane + 64];
            n2 = ((const float4*)xn)[lane + 128];
            n3 = ((const float4*)xn)[192 + (lane & 3)];
        }

        // interleaved slice of the constant output fill: 3 stores/thread/iter
        #pragma unroll
        for (int k = 0; k < 3; ++k) {
            const int jj = tid + (p * 3 + k) * 256;   // < 6144 always
            const float vv = sconst[jj / 196];
            ((float4*)ob)[jj] = make_float4(vv, vv, vv, vv);
        }

        // lane-local abs-max of the 16 register elements
        float m = fmaxf(fmaxf(fmaxf(fabsf(v0.x), fabsf(v0.y)),
                              fmaxf(fabsf(v0.z), fabsf(v0.w))),
                        fmaxf(fmaxf(fabsf(v1.x), fabsf(v1.y)),
                              fmaxf(fabsf(v1.z), fabsf(v1.w))));
        m = fmaxf(m, fmaxf(fmaxf(fabsf(v2.x), fabsf(v2.y)),
                           fmaxf(fabsf(v2.z), fabsf(v2.w))));
        m = fmaxf(m, fmaxf(fmaxf(fabsf(v3.x), fabsf(v3.y)),
                           fmaxf(fabsf(v3.z), fabsf(v3.w))));

        const float2 ab  = sAB[wv * 8 + p];        // wave-uniform broadcast
        const bool   hot = fmaf(ab.x, m, ab.y) >= DW_THRESH * 0.999f;

        if (__any(hot)) {
            // ---- exact path (rare): stage to LDS and convolve ----
            const int   c    = word * 32 + wv * 8 + p;
            const float inv1 = bn1_g[c] * rsqrtf(bn1_v[c] + EPS);
            const float c1   = (dw_b[c] - bn1_m[c]) * inv1 + bn1_b[c];
            float w9[9];
            #pragma unroll
            for (int k = 0; k < 9; ++k) w9[k] = dw_w[c * 9 + k];

            ((float4*)tp)[lane]       = v0;
            ((float4*)tp)[lane + 64]  = v1;
            ((float4*)tp)[lane + 128] = v2;
            if (lane < 4) ((float4*)tp)[lane + 192] = v3;

            float amax_l = 0.0f;   // ReLU folded into fmax
            float2 La = *(const float2*)&tp[(r0 - 1) * 28 + pL];
            float2 Ca = *(const float2*)&tp[(r0 - 1) * 28 + pC];
            float2 Ra = *(const float2*)&tp[(r0 - 1) * 28 + pR];
            float2 Lb = *(const float2*)&tp[r0 * 28 + pL];
            float2 Cb = *(const float2*)&tp[r0 * 28 + pC];
            float2 Rb = *(const float2*)&tp[r0 * 28 + pR];
            float am1 = La.y * mLm, a0 = Ca.x, a1 = Ca.y, a2 = Ra.x * mRm;
            float bm1 = Lb.y * mLm, b0 = Cb.x, b1 = Cb.y, b2 = Rb.x * mRm;
            #pragma unroll
            for (int rr = 0; rr < 7; ++rr) {
                const int rc = r0 + rr + 1;
                float2 Lc = *(const float2*)&tp[rc * 28 + pL];
                float2 Cc = *(const float2*)&tp[rc * 28 + pC];
                float2 Rc = *(const float2*)&tp[rc * 28 + pR];
                float cm1 = Lc.y * mLm, cc0 = Cc.x, cc1 = Cc.y, cc2 = Rc.x * mRm;
                float acc0 =              w9[0] * am1;
                acc0 = fmaf(w9[1], a0,  acc0);
                acc0 = fmaf(w9[2], a1,  acc0);
                acc0 = fmaf(w9[3], bm1, acc0);
                acc0 = fmaf(w9[4], b0,  acc0);
                acc0 = fmaf(w9[5], b1,  acc0);
                acc0 = fmaf(w9[6], cm1, acc0);
                acc0 = fmaf(w9[7], cc0, acc0);
                acc0 = fmaf(w9[8], cc1, acc0);
                float acc1 =              w9[0] * a0;
                acc1 = fmaf(w9[1], a1,  acc1);
                acc1 = fmaf(w9[2], a2,  acc1);
                acc1 = fmaf(w9[3], b0,  acc1);
                acc1 = fmaf(w9[4], b1,  acc1);
                acc1 = fmaf(w9[5], b2,  acc1);
                acc1 = fmaf(w9[6], cc0, acc1);
                acc1 = fmaf(w9[7], cc1, acc1);
                acc1 = fmaf(w9[8], cc2, acc1);
                const float t0 = fmaf(acc0, inv1, c1);
                const float t1 = fmaf(acc1, inv1, c1);
                amax_l = fmaxf(amax_l, fmaxf(t0, t1));
                am1 = bm1; a0 = b0; a1 = b1; a2 = b2;
                bm1 = cm1; b0 = cc0; b1 = cc1; b2 = cc2;
            }
            #pragma unroll
            for (int off = 1; off < 64; off <<= 1)
                amax_l = fmaxf(amax_l, __shfl_xor(amax_l, off, 64));
            if (amax_l >= DW_THRESH) flags |= (1u << p);
        }
        // else: provably pruned, bit stays 0

        if (p < 7) { v0 = n0; v1 = n1; v2 = n2; v3 = n3; }
    }

    // fill remainder: slots 6144..6271 (threads 0..127)
    if (tid < 128) {
        const int jj = 6144 + tid;
        const float vv = sconst[jj / 196];
        ((float4*)ob)[jj] = make_float4(vv, vv, vv, vv);
    }

    if (lane == 0) wflags[wv] = flags;
    __syncthreads();
    if (tid == 0)
        mask[bid] = wflags[0] | (wflags[1] << 8) | (wflags[2] << 16)
                  | (wflags[3] << 24);
}

// ===========================================================================
// Kernel B: fixup. One block per BATCH (64 blocks). Reads the batch's 16 mask
// words (one 64 B line); all zero (actual case) -> exit. Otherwise exact
// pointwise recompute of all 16 output groups of this batch (correctness-only
// path, never taken with this data).
// ===========================================================================
__global__ __launch_bounds__(256) void fixup_kernel(
    const float* __restrict__ x,
    const float* __restrict__ dw_w, const float* __restrict__ dw_b,
    const float* __restrict__ bn1_g, const float* __restrict__ bn1_b,
    const float* __restrict__ bn1_m, const float* __restrict__ bn1_v,
    const float* __restrict__ pw_w, const float* __restrict__ pw_b,
    const float* __restrict__ bn2_g, const float* __restrict__ bn2_b,
    const float* __restrict__ bn2_m, const float* __restrict__ bn2_v,
    const unsigned int* __restrict__ mask,
    float* __restrict__ out)
{
    const int b   = blockIdx.x;            // batch
    const int tid = threadIdx.x;

    __shared__ unsigned int smask[16];
    __shared__ float sx[30 * 30];
    __shared__ float red[4];
    __shared__ float sfinal;

    if (tid < 16) smask[tid] = mask[(b << 4) + tid];
    __syncthreads();

    unsigned int any = 0;
    #pragma unroll
    for (int k = 0; k < 16; ++k) any |= smask[k];
    if (any == 0u) return;                 // actual case: constants stand

    // ---- general path: exact pointwise recompute (correctness only) ----
    for (int i = tid; i < 900; i += 256) sx[i] = 0.0f;   // halo zeros
    __syncthreads();
    const int xx = tid % 28;
    const int ys = (tid / 28) * 4;

    for (int og = 0; og < 16; ++og) {
        float* ob = out + ((size_t)(b * 16 + og)) * 32 * HWPLANE;

        for (int col = 0; col < 32; ++col) {
            const int co = og * 32 + col;
            const float inv2 = bn2_g[co] * rsqrtf(bn2_v[co] + EPS);
            const float c2   = (pw_b[co] - bn2_m[co]) * inv2 + bn2_b[co];
            float acc[4] = {0.f, 0.f, 0.f, 0.f};

            for (int ci = 0; ci < CIN; ++ci) {
                if (!((smask[ci >> 5] >> (ci & 31)) & 1u)) continue;  // uniform
                __syncthreads();   // protect sx before overwrite
                const float* xp = x + ((size_t)(b * CIN + ci)) * HWPLANE;
                if (tid < 196) {
                    const float4 vv = ((const float4*)xp)[tid];
                    const int y  = tid / 7;
                    const int x0 = (tid % 7) * 4;
                    float* d = &sx[(y + 1) * 30 + x0 + 1];
                    d[0] = vv.x; d[1] = vv.y; d[2] = vv.z; d[3] = vv.w;
                }
                const float inv1 = bn1_g[ci] * rsqrtf(bn1_v[ci] + EPS);
                const float c1   = (dw_b[ci] - bn1_m[ci]) * inv1 + bn1_b[ci];
                const float wco  = pw_w[co * CIN + ci];
                float w9[9];
                #pragma unroll
                for (int k = 0; k < 9; ++k) w9[k] = dw_w[ci * 9 + k];
                __syncthreads();
                if (tid < 196) {
                    float r[6][3];
                    #pragma unroll
                    for (int jj = 0; jj < 6; ++jj)
                        #pragma unroll
                        for (int k = 0; k < 3; ++k)
                            r[jj][k] = sx[(ys + jj) * 30 + xx + k];
                    #pragma unroll
                    for (int i = 0; i < 4; ++i) {
                        float a = 0.0f;
                        #pragma unroll
                        for (int dy = 0; dy < 3; ++dy)
                            #pragma unroll
                            for (int dx = 0; dx < 3; ++dx)
                                a = fmaf(w9[dy * 3 + dx], r[i + dy][dx], a);
                        float hv = fmaf(a, inv1, c1);
                        hv = hv > 0.0f ? hv : 0.0f;
                        acc[i] = fmaf(wco, hv, acc[i]);
                    }
                }
            }

            float vout[4];
            float amax = 0.0f;
            if (tid < 196) {
                #pragma unroll
                for (int i = 0; i < 4; ++i) {
                    float t = fmaf(acc[i], inv2, c2);
                    t = t > 0.0f ? t : 0.0f;
                    vout[i] = t;
                    amax = fmaxf(amax, t);
                }
            }
            #pragma unroll
            for (int off = 32; off > 0; off >>= 1)
                amax = fmaxf(amax, __shfl_down(amax, off, 64));
            if ((tid & 63) == 0) red[tid >> 6] = amax;
            __syncthreads();
            if (tid == 0)
                sfinal = fmaxf(fmaxf(red[0], red[1]), fmaxf(red[2], red[3]));
            __syncthreads();
            const bool zero = sfinal < PW_THRESH;
            if (tid < 196) {
                float* op = ob + (size_t)col * HWPLANE;
                #pragma unroll
                for (int i = 0; i < 4; ++i)
                    op[(ys + i) * 28 + xx] = zero ? 0.0f : vout[i];
            }
            __syncthreads();
        }
    }
}

extern "C" void kernel_launch(void* const* d_in, const int* in_sizes, int n_in,
                              void* d_out, int out_size, void* d_ws, size_t ws_size,
                              hipStream_t stream)
{
    const float* x     = (const float*)d_in[0];
    const float* dw_w  = (const float*)d_in[1];
    const float* dw_b  = (const float*)d_in[2];
    const float* bn1_g = (const float*)d_in[3];
    const float* bn1_b = (const float*)d_in[4];
    const float* bn1_m = (const float*)d_in[5];
    const float* bn1_v = (const float*)d_in[6];
    const float* pw_w  = (const float*)d_in[7];
    const float* pw_b  = (const float*)d_in[8];
    const float* bn2_g = (const float*)d_in[9];
    const float* bn2_b = (const float*)d_in[10];
    const float* bn2_m = (const float*)d_in[11];
    const float* bn2_v = (const float*)d_in[12];

    unsigned int* mask = (unsigned int*)d_ws;   // 64 x 16 words, all written
    float* out = (float*)d_out;

    flags_fill_kernel<<<64 * 16, 256, 0, stream>>>(
        x, dw_w, dw_b, bn1_g, bn1_b, bn1_m, bn1_v,
        pw_b, bn2_g, bn2_b, bn2_m, bn2_v, mask, out);

    fixup_kernel<<<64, 256, 0, stream>>>(
        x, dw_w, dw_b, bn1_g, bn1_b, bn1_m, bn1_v,
        pw_w, pw_b, bn2_g, bn2_b, bn2_m, bn2_v, mask, out);
}

// Round 10
// 34.721 us; speedup vs baseline: 1.0273x; 1.0273x over previous
//
#include <hip/hip_runtime.h>

#define EPS        1e-5f
#define DW_THRESH  4.0f
#define PW_THRESH  0.001f
#define CIN        512
#define COUT       512
#define HWPLANE    784   // 28*28

// ===========================================================================
// Kernel A: per-(b,c) plane flags + speculative constant output fill.
// One block per (b, 32-channel word): 1024 blocks, 4 waves, wave-autonomous
// flags loop (ballot bound check, exact conv fallback), then mask word store
// and a contiguous 100 KB constant-fill burst of this block's 32 output
// planes (round-8 structure: fill AFTER the read loop — interleaving stores
// into the prefetch stream measurably hurt). Kernel B fixes up iff mask != 0.
// ===========================================================================
__global__ __launch_bounds__(256) void flags_fill_kernel(
    const float* __restrict__ x,
    const float* __restrict__ dw_w, const float* __restrict__ dw_b,
    const float* __restrict__ bn1_g, const float* __restrict__ bn1_b,
    const float* __restrict__ bn1_m, const float* __restrict__ bn1_v,
    const float* __restrict__ pw_b,
    const float* __restrict__ bn2_g, const float* __restrict__ bn2_b,
    const float* __restrict__ bn2_m, const float* __restrict__ bn2_v,
    unsigned int* __restrict__ mask,
    float* __restrict__ out)
{
    const int bid  = blockIdx.x;       // b*16 + word
    const int word = bid & 15;
    const int tid  = threadIdx.x;
    const int wv   = tid >> 6;         // wave 0..3
    const int lane = tid & 63;

    __shared__ float tile[4][30 * 28]; // per-wave padded plane (rows -1..28)
    __shared__ float2 sAB[32];         // per-channel (A,B) bound constants
    __shared__ float  sconst[32];      // per-output-channel constant value
    __shared__ unsigned int wflags[4];

    float* tp = tile[wv] + 28;         // tp[r*28 + c], r in [-1, 28]

    // per-channel constants (once per block)
    if (tid < 32) {
        const int   c    = word * 32 + tid;
        const float inv1 = bn1_g[c] * rsqrtf(bn1_v[c] + EPS);
        const float c1   = (dw_b[c] - bn1_m[c]) * inv1 + bn1_b[c];
        float S = 0.0f;
        #pragma unroll
        for (int k = 0; k < 9; ++k) S += fabsf(dw_w[c * 9 + k]);
        sAB[tid] = make_float2(fabsf(inv1) * S, c1);

        // speculative output constant for co = word*32 + tid
        const float inv2 = bn2_g[c] * rsqrtf(bn2_v[c] + EPS);
        const float c2   = (pw_b[c] - bn2_m[c]) * inv2 + bn2_b[c];
        float vv = c2 > 0.0f ? c2 : 0.0f;          // ReLU
        if (vv < PW_THRESH) vv = 0.0f;             // constant-plane prune
        sconst[tid] = vv;
    }
    // zero the two halo rows of the wave tile
    if (lane < 28)      tile[wv][lane] = 0.0f;                 // row -1
    else if (lane < 56) tile[wv][29 * 28 + lane - 28] = 0.0f;  // row 28
    __syncthreads();

    const float* xw = x + ((size_t)bid * 32 + (size_t)wv * 8) * HWPLANE;

    // conv work assignment (exact path): lane -> (col pair j, row group g)
    const int   j   = lane % 14;                   // cols 2j, 2j+1
    const int   gg  = lane / 14;                   // 0..4 (56-63 duplicate g=3)
    const int   r0  = (gg < 4 ? gg : 3) * 7;       // rows r0 .. r0+6
    const float mLm = (j > 0)  ? 1.0f : 0.0f;
    const float mRm = (j < 13) ? 1.0f : 0.0f;
    const int   pL  = (j > 0)  ? 2 * j - 2 : 0;    // clamped (masked)
    const int   pC  = 2 * j;
    const int   pR  = (j < 13) ? 2 * j + 2 : 24;   // clamped (masked)

    // prefetch plane 0 (196 float4 slots; slot 192+(lane&3) duplicated)
    float4 v0 = ((const float4*)xw)[lane];
    float4 v1 = ((const float4*)xw)[lane + 64];
    float4 v2 = ((const float4*)xw)[lane + 128];
    float4 v3 = ((const float4*)xw)[192 + (lane & 3)];

    unsigned int flags = 0;

    for (int p = 0; p < 8; ++p) {
        // prefetch next plane first (overlaps everything below)
        float4 n0, n1, n2, n3;
        if (p < 7) {
            const float* xn = xw + (size_t)(p + 1) * HWPLANE;
            n0 = ((const float4*)xn)[lane];
            n1 = ((const float4*)xn)[lane + 64];
            n2 = ((const float4*)xn)[lane + 128];
            n3 = ((const float4*)xn)[192 + (lane & 3)];
        }

        // lane-local abs-max of the 16 register elements
        float m = fmaxf(fmaxf(fmaxf(fabsf(v0.x), fabsf(v0.y)),
                              fmaxf(fabsf(v0.z), fabsf(v0.w))),
                        fmaxf(fmaxf(fabsf(v1.x), fabsf(v1.y)),
                              fmaxf(fabsf(v1.z), fabsf(v1.w))));
        m = fmaxf(m, fmaxf(fmaxf(fabsf(v2.x), fabsf(v2.y)),
                           fmaxf(fabsf(v2.z), fabsf(v2.w))));
        m = fmaxf(m, fmaxf(fmaxf(fabsf(v3.x), fabsf(v3.y)),
                           fmaxf(fabsf(v3.z), fabsf(v3.w))));

        const float2 ab  = sAB[wv * 8 + p];        // wave-uniform broadcast
        const bool   hot = fmaf(ab.x, m, ab.y) >= DW_THRESH * 0.999f;

        if (__any(hot)) {
            // ---- exact path (rare): stage to LDS and convolve ----
            const int   c    = word * 32 + wv * 8 + p;
            const float inv1 = bn1_g[c] * rsqrtf(bn1_v[c] + EPS);
            const float c1   = (dw_b[c] - bn1_m[c]) * inv1 + bn1_b[c];
            float w9[9];
            #pragma unroll
            for (int k = 0; k < 9; ++k) w9[k] = dw_w[c * 9 + k];

            ((float4*)tp)[lane]       = v0;
            ((float4*)tp)[lane + 64]  = v1;
            ((float4*)tp)[lane + 128] = v2;
            if (lane < 4) ((float4*)tp)[lane + 192] = v3;

            float amax_l = 0.0f;   // ReLU folded into fmax
            float2 La = *(const float2*)&tp[(r0 - 1) * 28 + pL];
            float2 Ca = *(const float2*)&tp[(r0 - 1) * 28 + pC];
            float2 Ra = *(const float2*)&tp[(r0 - 1) * 28 + pR];
            float2 Lb = *(const float2*)&tp[r0 * 28 + pL];
            float2 Cb = *(const float2*)&tp[r0 * 28 + pC];
            float2 Rb = *(const float2*)&tp[r0 * 28 + pR];
            float am1 = La.y * mLm, a0 = Ca.x, a1 = Ca.y, a2 = Ra.x * mRm;
            float bm1 = Lb.y * mLm, b0 = Cb.x, b1 = Cb.y, b2 = Rb.x * mRm;
            #pragma unroll
            for (int rr = 0; rr < 7; ++rr) {
                const int rc = r0 + rr + 1;
                float2 Lc = *(const float2*)&tp[rc * 28 + pL];
                float2 Cc = *(const float2*)&tp[rc * 28 + pC];
                float2 Rc = *(const float2*)&tp[rc * 28 + pR];
                float cm1 = Lc.y * mLm, cc0 = Cc.x, cc1 = Cc.y, cc2 = Rc.x * mRm;
                float acc0 =              w9[0] * am1;
                acc0 = fmaf(w9[1], a0,  acc0);
                acc0 = fmaf(w9[2], a1,  acc0);
                acc0 = fmaf(w9[3], bm1, acc0);
                acc0 = fmaf(w9[4], b0,  acc0);
                acc0 = fmaf(w9[5], b1,  acc0);
                acc0 = fmaf(w9[6], cm1, acc0);
                acc0 = fmaf(w9[7], cc0, acc0);
                acc0 = fmaf(w9[8], cc1, acc0);
                float acc1 =              w9[0] * a0;
                acc1 = fmaf(w9[1], a1,  acc1);
                acc1 = fmaf(w9[2], a2,  acc1);
                acc1 = fmaf(w9[3], b0,  acc1);
                acc1 = fmaf(w9[4], b1,  acc1);
                acc1 = fmaf(w9[5], b2,  acc1);
                acc1 = fmaf(w9[6], cc0, acc1);
                acc1 = fmaf(w9[7], cc1, acc1);
                acc1 = fmaf(w9[8], cc2, acc1);
                const float t0 = fmaf(acc0, inv1, c1);
                const float t1 = fmaf(acc1, inv1, c1);
                amax_l = fmaxf(amax_l, fmaxf(t0, t1));
                am1 = bm1; a0 = b0; a1 = b1; a2 = b2;
                bm1 = cm1; b0 = cc0; b1 = cc1; b2 = cc2;
            }
            #pragma unroll
            for (int off = 1; off < 64; off <<= 1)
                amax_l = fmaxf(amax_l, __shfl_xor(amax_l, off, 64));
            if (amax_l >= DW_THRESH) flags |= (1u << p);
        }
        // else: provably pruned, bit stays 0

        if (p < 7) { v0 = n0; v1 = n1; v2 = n2; v3 = n3; }
    }

    if (lane == 0) wflags[wv] = flags;
    __syncthreads();
    if (tid == 0)
        mask[bid] = wflags[0] | (wflags[1] << 8) | (wflags[2] << 16)
                  | (wflags[3] << 24);

    // ---- speculative constant fill: one contiguous store burst ----
    float* ob = out + (size_t)bid * 32 * HWPLANE;
    for (int jj = tid; jj < 6272; jj += 256) {      // 32 planes * 196 float4
        const float vv = sconst[jj / 196];
        ((float4*)ob)[jj] = make_float4(vv, vv, vv, vv);
    }
}

// ===========================================================================
// Kernel B: fixup. One block per BATCH (64 blocks). Reads the batch's 16 mask
// words (one 64 B line); all zero (actual case) -> exit. Otherwise exact
// pointwise recompute of all 16 output groups of this batch (correctness-only
// path, never taken with this data).
// ===========================================================================
__global__ __launch_bounds__(256) void fixup_kernel(
    const float* __restrict__ x,
    const float* __restrict__ dw_w, const float* __restrict__ dw_b,
    const float* __restrict__ bn1_g, const float* __restrict__ bn1_b,
    const float* __restrict__ bn1_m, const float* __restrict__ bn1_v,
    const float* __restrict__ pw_w, const float* __restrict__ pw_b,
    const float* __restrict__ bn2_g, const float* __restrict__ bn2_b,
    const float* __restrict__ bn2_m, const float* __restrict__ bn2_v,
    const unsigned int* __restrict__ mask,
    float* __restrict__ out)
{
    const int b   = blockIdx.x;            // batch
    const int tid = threadIdx.x;

    __shared__ unsigned int smask[16];
    __shared__ float sx[30 * 30];
    __shared__ float red[4];
    __shared__ float sfinal;

    if (tid < 16) smask[tid] = mask[(b << 4) + tid];
    __syncthreads();

    unsigned int any = 0;
    #pragma unroll
    for (int k = 0; k < 16; ++k) any |= smask[k];
    if (any == 0u) return;                 // actual case: constants stand

    // ---- general path: exact pointwise recompute (correctness only) ----
    for (int i = tid; i < 900; i += 256) sx[i] = 0.0f;   // halo zeros
    __syncthreads();
    const int xx = tid % 28;
    const int ys = (tid / 28) * 4;

    for (int og = 0; og < 16; ++og) {
        float* ob = out + ((size_t)(b * 16 + og)) * 32 * HWPLANE;

        for (int col = 0; col < 32; ++col) {
            const int co = og * 32 + col;
            const float inv2 = bn2_g[co] * rsqrtf(bn2_v[co] + EPS);
            const float c2   = (pw_b[co] - bn2_m[co]) * inv2 + bn2_b[co];
            float acc[4] = {0.f, 0.f, 0.f, 0.f};

            for (int ci = 0; ci < CIN; ++ci) {
                if (!((smask[ci >> 5] >> (ci & 31)) & 1u)) continue;  // uniform
                __syncthreads();   // protect sx before overwrite
                const float* xp = x + ((size_t)(b * CIN + ci)) * HWPLANE;
                if (tid < 196) {
                    const float4 vv = ((const float4*)xp)[tid];
                    const int y  = tid / 7;
                    const int x0 = (tid % 7) * 4;
                    float* d = &sx[(y + 1) * 30 + x0 + 1];
                    d[0] = vv.x; d[1] = vv.y; d[2] = vv.z; d[3] = vv.w;
                }
                const float inv1 = bn1_g[ci] * rsqrtf(bn1_v[ci] + EPS);
                const float c1   = (dw_b[ci] - bn1_m[ci]) * inv1 + bn1_b[ci];
                const float wco  = pw_w[co * CIN + ci];
                float w9[9];
                #pragma unroll
                for (int k = 0; k < 9; ++k) w9[k] = dw_w[ci * 9 + k];
                __syncthreads();
                if (tid < 196) {
                    float r[6][3];
                    #pragma unroll
                    for (int jj = 0; jj < 6; ++jj)
                        #pragma unroll
                        for (int k = 0; k < 3; ++k)
                            r[jj][k] = sx[(ys + jj) * 30 + xx + k];
                    #pragma unroll
                    for (int i = 0; i < 4; ++i) {
                        float a = 0.0f;
                        #pragma unroll
                        for (int dy = 0; dy < 3; ++dy)
                            #pragma unroll
                            for (int dx = 0; dx < 3; ++dx)
                                a = fmaf(w9[dy * 3 + dx], r[i + dy][dx], a);
                        float hv = fmaf(a, inv1, c1);
                        hv = hv > 0.0f ? hv : 0.0f;
                        acc[i] = fmaf(wco, hv, acc[i]);
                    }
                }
            }

            float vout[4];
            float amax = 0.0f;
            if (tid < 196) {
                #pragma unroll
                for (int i = 0; i < 4; ++i) {
                    float t = fmaf(acc[i], inv2, c2);
                    t = t > 0.0f ? t : 0.0f;
                    vout[i] = t;
                    amax = fmaxf(amax, t);
                }
            }
            #pragma unroll
            for (int off = 32; off > 0; off >>= 1)
                amax = fmaxf(amax, __shfl_down(amax, off, 64));
            if ((tid & 63) == 0) red[tid >> 6] = amax;
            __syncthreads();
            if (tid == 0)
                sfinal = fmaxf(fmaxf(red[0], red[1]), fmaxf(red[2], red[3]));
            __syncthreads();
            const bool zero = sfinal < PW_THRESH;
            if (tid < 196) {
                float* op = ob + (size_t)col * HWPLANE;
                #pragma unroll
                for (int i = 0; i < 4; ++i)
                    op[(ys + i) * 28 + xx] = zero ? 0.0f : vout[i];
            }
            __syncthreads();
        }
    }
}

extern "C" void kernel_launch(void* const* d_in, const int* in_sizes, int n_in,
                              void* d_out, int out_size, void* d_ws, size_t ws_size,
                              hipStream_t stream)
{
    const float* x     = (const float*)d_in[0];
    const float* dw_w  = (const float*)d_in[1];
    const float* dw_b  = (const float*)d_in[2];
    const float* bn1_g = (const float*)d_in[3];
    const float* bn1_b = (const float*)d_in[4];
    const float* bn1_m = (const float*)d_in[5];
    const float* bn1_v = (const float*)d_in[6];
    const float* pw_w  = (const float*)d_in[7];
    const float* pw_b  = (const float*)d_in[8];
    const float* bn2_g = (const float*)d_in[9];
    const float* bn2_b = (const float*)d_in[10];
    const float* bn2_m = (const float*)d_in[11];
    const float* bn2_v = (const float*)d_in[12];

    unsigned int* mask = (unsigned int*)d_ws;   // 64 x 16 words, all written
    float* out = (float*)d_out;

    flags_fill_kernel<<<64 * 16, 256, 0, stream>>>(
        x, dw_w, dw_b, bn1_g, bn1_b, bn1_m, bn1_v,
        pw_b, bn2_g, bn2_b, bn2_m, bn2_v, mask, out);

    fixup_kernel<<<64, 256, 0, stream>>>(
        x, dw_w, dw_b, bn1_g, bn1_b, bn1_m, bn1_v,
        pw_w, pw_b, bn2_g, bn2_b, bn2_m, bn2_v, mask, out);
}